// Round 4
// baseline (1828.509 us; speedup 1.0000x reference)
//
#include <hip/hip_runtime.h>
#include <math.h>

#define DD 512

typedef __attribute__((ext_vector_type(8))) short short8;
typedef __attribute__((ext_vector_type(4))) float f32x4;

__device__ __forceinline__ unsigned short f2bf(float x) {
  unsigned u = __float_as_uint(x);
  u = (u + 0x7FFFu + ((u >> 16) & 1u)) >> 16;  // RNE; no NaN expected
  return (unsigned short)u;
}
__device__ __forceinline__ float bf2f(unsigned short b) {
  return __uint_as_float(((unsigned)b) << 16);
}

__device__ __forceinline__ void gll16(const void* g, void* l) {
  __builtin_amdgcn_global_load_lds(
      (const __attribute__((address_space(1))) unsigned int*)g,
      (__attribute__((address_space(3))) unsigned int*)l, 16, 0, 0);
}

// ---------------------------------------------------------------------------
// k_prep: per-row sq-norms -> atomicMax c_max; fp32->bf16 casts; column sums.
// One wave per 16 rows (64 rows/block). N,M multiples of 64.
// ---------------------------------------------------------------------------
__global__ __launch_bounds__(256) void k_prep(
    const float* __restrict__ XB, const float* __restrict__ Xbar,
    unsigned short* __restrict__ XBb, unsigned short* __restrict__ Xbarb,
    float* __restrict__ cmax, float* __restrict__ sumXB,
    float* __restrict__ sumXbar, int N, int M) {
  const int wid = threadIdx.x >> 6, lane = threadIdx.x & 63;
  int rowBase = blockIdx.x * 64 + wid * 16;
  const float* src;
  unsigned short* dst;
  float* sumDst;
  int r0;
  if (rowBase < N) { src = XB;   dst = XBb;   sumDst = sumXB;   r0 = rowBase; }
  else             { src = Xbar; dst = Xbarb; sumDst = sumXbar; r0 = rowBase - N; }
  float ca[8] = {0, 0, 0, 0, 0, 0, 0, 0};
  float rmax = 0.f;
  for (int i = 0; i < 16; ++i) {
    size_t base = (size_t)(r0 + i) * DD + lane * 8;
    float4 v0 = *(const float4*)&src[base];
    float4 v1 = *(const float4*)&src[base + 4];
    *(ushort4*)&dst[base]     = make_ushort4(f2bf(v0.x), f2bf(v0.y), f2bf(v0.z), f2bf(v0.w));
    *(ushort4*)&dst[base + 4] = make_ushort4(f2bf(v1.x), f2bf(v1.y), f2bf(v1.z), f2bf(v1.w));
    float ss = v0.x * v0.x + v0.y * v0.y + v0.z * v0.z + v0.w * v0.w +
               v1.x * v1.x + v1.y * v1.y + v1.z * v1.z + v1.w * v1.w;
    for (int k = 32; k; k >>= 1) ss += __shfl_xor(ss, k, 64);
    rmax = fmaxf(rmax, ss);
    ca[0] += v0.x; ca[1] += v0.y; ca[2] += v0.z; ca[3] += v0.w;
    ca[4] += v1.x; ca[5] += v1.y; ca[6] += v1.z; ca[7] += v1.w;
  }
  if (lane == 0) atomicMax((int*)cmax, __float_as_int(rmax));  // positive floats: int order == float order
#pragma unroll
  for (int j = 0; j < 8; ++j) atomicAdd(&sumDst[lane * 8 + j], ca[j]);
}

// ---------------------------------------------------------------------------
// k_transpose: fp32 [R][C] -> bf16 transposed [C][R], 64x64 LDS tiles.
// ---------------------------------------------------------------------------
__global__ __launch_bounds__(256) void k_transpose(
    const float* __restrict__ in, unsigned short* __restrict__ out, int R, int C) {
  __shared__ float tile[64][65];
  const int r0 = blockIdx.y * 64, c0 = blockIdx.x * 64;
  const int t = threadIdx.x;
  {
    const int rl = t >> 4, c4 = (t & 15) * 4;
#pragma unroll
    for (int k = 0; k < 4; ++k) {
      float4 v = *(const float4*)&in[(size_t)(r0 + rl + 16 * k) * C + c0 + c4];
      tile[rl + 16 * k][c4 + 0] = v.x;
      tile[rl + 16 * k][c4 + 1] = v.y;
      tile[rl + 16 * k][c4 + 2] = v.z;
      tile[rl + 16 * k][c4 + 3] = v.w;
    }
  }
  __syncthreads();
  {
    const int cl = t >> 2, rs = (t & 3) * 16;
    short8 s0, s1;
#pragma unroll
    for (int i = 0; i < 8; ++i) s0[i] = (short)f2bf(tile[rs + i][cl]);
#pragma unroll
    for (int i = 0; i < 8; ++i) s1[i] = (short)f2bf(tile[rs + 8 + i][cl]);
    size_t ob = (size_t)(c0 + cl) * R + r0 + rs;
    *(short8*)&out[ob] = s0;
    *(short8*)&out[ob + 8] = s1;
  }
}

// ---------------------------------------------------------------------------
// Shared NT-GEMM core: 128x128 tile, BK=64, 256 thr (4 waves in 2x2),
// 16x16x32 bf16 MFMA, acc 4x4 frags/wave. Both operands row-major, k-contig.
// LDS staged via global_load_lds width=16 with XOR-16B-chunk swizzle applied
// on the GLOBAL source (LDS dest stays linear); ds_read applies same XOR.
// ---------------------------------------------------------------------------
__device__ __forceinline__ void gemm_core(
    const unsigned short* __restrict__ A, const unsigned short* __restrict__ B,
    int lda, int ldb, size_t arow0, size_t brow0, int kbase, int KT,
    unsigned short* sh, f32x4 acc[4][4]) {
  unsigned short* lA = sh;
  unsigned short* lB = sh + 8192;
  const int t = threadIdx.x, lane = t & 63, wid = t >> 6;
  const int frow = lane & 15, fgrp = lane >> 4;
  const int wr = (wid >> 1) * 64, wc = (wid & 1) * 64;
  for (int kt = 0; kt < KT; ++kt) {
    const int k0 = kbase + kt * 64;
    // stage A,B: 1024 16B-chunks each, 4 issues/thread/matrix
#pragma unroll
    for (int i = 0; i < 4; ++i) {
      int c4 = i * 256 + t;
      int r = c4 >> 3, c = c4 & 7;
      int cg = c ^ (r & 7);  // pre-swizzled global source; LDS linear
      gll16(&A[(arow0 + r) * (size_t)lda + k0 + cg * 8], &lA[(i * 256 + wid * 64) * 8]);
      gll16(&B[(brow0 + r) * (size_t)ldb + k0 + cg * 8], &lB[(i * 256 + wid * 64) * 8]);
    }
    __syncthreads();  // compiler drains vmcnt before barrier
#pragma unroll
    for (int kk = 0; kk < 2; ++kk) {
      short8 af[4], bf[4];
#pragma unroll
      for (int f = 0; f < 4; ++f) {
        int ra = wr + f * 16 + frow;
        int ca = (kk * 4 + fgrp) ^ (ra & 7);
        af[f] = *(const short8*)&lA[ra * 64 + ca * 8];
        int rb = wc + f * 16 + frow;
        int cb = (kk * 4 + fgrp) ^ (rb & 7);
        bf[f] = *(const short8*)&lB[rb * 64 + cb * 8];
      }
#pragma unroll
      for (int fr = 0; fr < 4; ++fr)
#pragma unroll
        for (int fc = 0; fc < 4; ++fc)
          acc[fr][fc] = __builtin_amdgcn_mfma_f32_16x16x32_bf16(af[fr], bf[fc], acc[fr][fc], 0, 0, 0);
    }
    __syncthreads();
  }
}

// ---------------------------------------------------------------------------
// k_scores (per m-chunk): E_q = expm1(scores/(sqrt(D)*cmax)) -> E_q[N][MQ]
// and ET_q[MQ][N] (bf16), plus rowsumE / colsumE atomic partials.
// ---------------------------------------------------------------------------
__global__ __launch_bounds__(256) void k_scores(
    const unsigned short* __restrict__ XBb, const unsigned short* __restrict__ Xbarb,
    unsigned short* __restrict__ E, unsigned short* __restrict__ ET,
    float* __restrict__ rowsumE, float* __restrict__ colsumE,
    const float* __restrict__ cmaxp, int N, int mq0, int MQ) {
  __shared__ __align__(16) unsigned short sh[17408];  // K-loop: 2x8192; epilogue: [128][136]
  f32x4 acc[4][4];
#pragma unroll
  for (int a = 0; a < 4; ++a)
#pragma unroll
    for (int b = 0; b < 4; ++b) acc[a][b] = (f32x4){0.f, 0.f, 0.f, 0.f};
  const size_t n0 = (size_t)blockIdx.y * 128;
  const int ml0 = blockIdx.x * 128;  // m-local within chunk
  gemm_core(XBb, Xbarb, DD, DD, n0, (size_t)(mq0 + ml0), 0, DD / 64, sh, acc);

  const float inv = 1.0f / (22.62741699796952f * cmaxp[0]);  // 1/(sqrt(512)*c_max)
  const int lane = threadIdx.x & 63, wid = threadIdx.x >> 6;
  const int frow = lane & 15, fgrp = lane >> 4;
  const int wr = (wid >> 1) * 64, wc = (wid & 1) * 64;
#pragma unroll
  for (int fr = 0; fr < 4; ++fr)
#pragma unroll
    for (int fc = 0; fc < 4; ++fc)
#pragma unroll
      for (int j = 0; j < 4; ++j) {
        int r = wr + fr * 16 + fgrp * 4 + j;   // C/D layout: row=(lane>>4)*4+j
        int c = wc + fc * 16 + frow;           //             col=lane&15
        sh[r * 136 + c] = f2bf(expm1f(acc[fr][fc][j] * inv));
      }
  __syncthreads();
  {  // E rows (half-row per thread) + rowsum
    const int r = threadIdx.x >> 1, h = threadIdx.x & 1;
    float rs = 0.f;
#pragma unroll
    for (int i = 0; i < 8; ++i) {
      short8 v = *(const short8*)&sh[r * 136 + h * 64 + i * 8];
#pragma unroll
      for (int j = 0; j < 8; ++j) rs += bf2f((unsigned short)v[j]);
      *(short8*)&E[(n0 + r) * (size_t)MQ + ml0 + h * 64 + i * 8] = v;
    }
    atomicAdd(&rowsumE[n0 + r], rs);
  }
  {  // ET columns (half-col per thread) + colsum
    const int c = threadIdx.x >> 1, v0 = (threadIdx.x & 1) * 64;
    float cs = 0.f;
#pragma unroll
    for (int i = 0; i < 8; ++i) {
      short8 s;
#pragma unroll
      for (int j = 0; j < 8; ++j) {
        unsigned short w = sh[(v0 + i * 8 + j) * 136 + c];
        cs += bf2f(w);
        s[j] = (short)w;
      }
      *(short8*)&ET[(size_t)(ml0 + c) * N + n0 + v0 + i * 8] = s;
    }
    atomicAdd(&colsumE[mq0 + ml0 + c], cs);
  }
}

// ---------------------------------------------------------------------------
// G3 per chunk: out1_raw[n][d] (store if accum==0, += otherwise).
// Division deferred to k_fin1.
// ---------------------------------------------------------------------------
__global__ __launch_bounds__(256) void k_gemm_acc(
    const unsigned short* __restrict__ A, const unsigned short* __restrict__ B,
    float* __restrict__ out, int lda, int ldb, int KT, int accum) {
  __shared__ __align__(16) unsigned short sh[16384];
  f32x4 acc[4][4];
#pragma unroll
  for (int a = 0; a < 4; ++a)
#pragma unroll
    for (int b = 0; b < 4; ++b) acc[a][b] = (f32x4){0.f, 0.f, 0.f, 0.f};
  const size_t a0 = (size_t)blockIdx.y * 128, b0 = (size_t)blockIdx.x * 128;
  gemm_core(A, B, lda, ldb, a0, b0, 0, KT, sh, acc);

  const int lane = threadIdx.x & 63, wid = threadIdx.x >> 6;
  const int frow = lane & 15, fgrp = lane >> 4;
  const int wr = (wid >> 1) * 64, wc = (wid & 1) * 64;
#pragma unroll
  for (int fr = 0; fr < 4; ++fr)
#pragma unroll
    for (int fc = 0; fc < 4; ++fc)
#pragma unroll
      for (int j = 0; j < 4; ++j) {
        size_t r = a0 + wr + fr * 16 + fgrp * 4 + j;
        size_t c = b0 + wc + fc * 16 + frow;
        size_t idx = r * DD + c;
        float v = acc[fr][fc][j];
        out[idx] = accum ? out[idx] + v : v;
      }
}

// ---------------------------------------------------------------------------
// G4 per chunk: partial[z][m_local][d] = (ET_q @ XBT)[m][d] over k-chunk z.
// Pure stores (no atomics).
// ---------------------------------------------------------------------------
__global__ __launch_bounds__(256) void k_gemm_part(
    const unsigned short* __restrict__ A, const unsigned short* __restrict__ B,
    float* __restrict__ part, int lda, int KT, int kchunk, int MQ) {
  __shared__ __align__(16) unsigned short sh[16384];
  f32x4 acc[4][4];
#pragma unroll
  for (int a = 0; a < 4; ++a)
#pragma unroll
    for (int b = 0; b < 4; ++b) acc[a][b] = (f32x4){0.f, 0.f, 0.f, 0.f};
  const size_t a0 = (size_t)blockIdx.y * 128, b0 = (size_t)blockIdx.x * 128;
  gemm_core(A, B, lda, lda, a0, b0, blockIdx.z * kchunk, KT, sh, acc);

  float* pz = part + (size_t)blockIdx.z * MQ * DD;
  const int lane = threadIdx.x & 63, wid = threadIdx.x >> 6;
  const int frow = lane & 15, fgrp = lane >> 4;
  const int wr = (wid >> 1) * 64, wc = (wid & 1) * 64;
#pragma unroll
  for (int fr = 0; fr < 4; ++fr)
#pragma unroll
    for (int fc = 0; fc < 4; ++fc)
#pragma unroll
      for (int j = 0; j < 4; ++j) {
        size_t r = a0 + wr + fr * 16 + fgrp * 4 + j;
        size_t c = b0 + wc + fc * 16 + frow;
        pz[r * DD + c] = acc[fr][fc][j];
      }
}

// out2 chunk: out2[m][d] = (sumXB[d] + sum_z partial[z][m][d]) / (Nf + colsumE[m])
__global__ void k_reduce2(const float* __restrict__ part, float* __restrict__ out2,
                          const float* __restrict__ sumXB, const float* __restrict__ colsumE,
                          int MQ, int Z, float Nf) {
  size_t idx4 = ((size_t)blockIdx.x * 256 + threadIdx.x) * 4;
  int ml = (int)(idx4 >> 9), d = (int)(idx4 & (DD - 1));
  float4 s = make_float4(0.f, 0.f, 0.f, 0.f);
  for (int z = 0; z < Z; ++z) {
    float4 p = *(const float4*)&part[(size_t)z * MQ * DD + idx4];
    s.x += p.x; s.y += p.y; s.z += p.z; s.w += p.w;
  }
  float4 sx = *(const float4*)&sumXB[d];
  float den = 1.0f / (Nf + colsumE[ml]);
  float4 o = make_float4((sx.x + s.x) * den, (sx.y + s.y) * den,
                         (sx.z + s.z) * den, (sx.w + s.w) * den);
  *(float4*)&out2[idx4] = o;
}

// out1 final: out1[n][d] = (sumXbar[d] + raw) / (Mf + rowsumE[n])
__global__ void k_fin1(float* __restrict__ o, const float* __restrict__ sumXbar,
                       const float* __restrict__ rowsumE, float Mf) {
  size_t idx4 = ((size_t)blockIdx.x * 256 + threadIdx.x) * 4;
  int n = (int)(idx4 >> 9), d = (int)(idx4 & (DD - 1));
  float4 raw = *(const float4*)&o[idx4];
  float4 sx = *(const float4*)&sumXbar[d];
  float den = 1.0f / (Mf + rowsumE[n]);
  float4 r = make_float4((sx.x + raw.x) * den, (sx.y + raw.y) * den,
                         (sx.z + raw.z) * den, (sx.w + raw.w) * den);
  *(float4*)&o[idx4] = r;
}

__global__ void k_wsmark(float* o, float a) { o[0] = a; }

// ---------------------------------------------------------------------------
extern "C" void kernel_launch(void* const* d_in, const int* in_sizes, int n_in,
                              void* d_out, int out_size, void* d_ws, size_t ws_size,
                              hipStream_t stream) {
  const float* XB = (const float*)d_in[0];
  const float* Xbar = (const float*)d_in[1];
  const int N = in_sizes[0] / DD;  // 32768
  const int M = in_sizes[1] / DD;  // 4096
  float* out = (float*)d_out;
  const int Z = 16, kchunk = N / Z, KT4 = kchunk / 64;

  // Pick largest m-chunk that fits the workspace.
  int MQ = 1024;
  size_t off = 0;
  char* ws = (char*)d_ws;
  auto plan = [&](int mq) {
    size_t o = 0;
    auto tk = [&](size_t b) { o = (o + b + 255) & ~(size_t)255; };
    tk(4); tk((size_t)N * 4); tk((size_t)M * 4); tk(DD * 4); tk(DD * 4);   // head
    tk((size_t)N * DD * 2); tk((size_t)M * DD * 2);                        // XBb, Xbarb
    tk((size_t)N * DD * 2); tk((size_t)M * DD * 2);                        // XBT, XbarT
    tk((size_t)N * mq * 2); tk((size_t)mq * N * 2);                        // E_q, ET_q
    tk((size_t)Z * mq * DD * 4);                                           // partials
    return o;
  };
  while (MQ > 128 && plan(MQ) > ws_size) MQ >>= 1;
  if (plan(MQ) > ws_size) {
    hipMemsetAsync(d_out, 0, (size_t)out_size * 4, stream);
    k_wsmark<<<1, 1, 0, stream>>>(out, (float)ws_size);
    return;
  }

  auto take = [&](size_t bytes) {
    char* p = ws + off;
    off = (off + bytes + 255) & ~(size_t)255;
    return p;
  };
  float* cmax = (float*)take(4);
  float* rowsumE = (float*)take((size_t)N * 4);
  float* colsumE = (float*)take((size_t)M * 4);
  float* sumXB = (float*)take(DD * 4);
  float* sumXbar = (float*)take(DD * 4);
  size_t headBytes = off;
  unsigned short* XBb = (unsigned short*)take((size_t)N * DD * 2);
  unsigned short* Xbarb = (unsigned short*)take((size_t)M * DD * 2);
  unsigned short* XBT = (unsigned short*)take((size_t)N * DD * 2);
  unsigned short* XbarT = (unsigned short*)take((size_t)M * DD * 2);
  unsigned short* E = (unsigned short*)take((size_t)N * MQ * 2);
  unsigned short* ET = (unsigned short*)take((size_t)MQ * N * 2);
  float* part = (float*)take((size_t)Z * MQ * DD * 4);

  hipMemsetAsync(ws, 0, headBytes, stream);  // zero cmax + all sum accumulators

  k_prep<<<(N + M) / 64, 256, 0, stream>>>(XB, Xbar, XBb, Xbarb, cmax, sumXB, sumXbar, N, M);
  k_transpose<<<dim3(DD / 64, N / 64), 256, 0, stream>>>(XB, XBT, N, DD);
  k_transpose<<<dim3(DD / 64, M / 64), 256, 0, stream>>>(Xbar, XbarT, M, DD);

  for (int mq0 = 0; mq0 < M; mq0 += MQ) {
    k_scores<<<dim3(MQ / 128, N / 128), 256, 0, stream>>>(
        XBb, Xbarb, E, ET, rowsumE, colsumE, cmax, N, mq0, MQ);
    k_gemm_acc<<<dim3(DD / 128, N / 128), 256, 0, stream>>>(
        E, XbarT + mq0, out, MQ, M, MQ / 64, mq0 > 0 ? 1 : 0);
    k_gemm_part<<<dim3(DD / 128, MQ / 128, Z), 256, 0, stream>>>(
        ET, XBT, part, N, KT4, kchunk, MQ);
    k_reduce2<<<(MQ * DD) / 1024, 256, 0, stream>>>(
        part, out + (size_t)N * DD + (size_t)mq0 * DD, sumXB, colsumE + mq0, MQ, Z, (float)N);
  }
  k_fin1<<<((size_t)N * DD) / 1024, 256, 0, stream>>>(out, sumXbar, rowsumE, (float)M);
}

// Round 5
// 1547.059 us; speedup vs baseline: 1.1819x; 1.1819x over previous
//
#include <hip/hip_runtime.h>
#include <math.h>

#define DD 512

typedef __attribute__((ext_vector_type(8))) short short8;
typedef __attribute__((ext_vector_type(4))) float f32x4;

__device__ __forceinline__ unsigned short f2bf(float x) {
  unsigned u = __float_as_uint(x);
  u = (u + 0x7FFFu + ((u >> 16) & 1u)) >> 16;  // RNE; no NaN expected
  return (unsigned short)u;
}
__device__ __forceinline__ float bf2f(unsigned short b) {
  return __uint_as_float(((unsigned)b) << 16);
}

__device__ __forceinline__ void gll16(const void* g, void* l) {
  __builtin_amdgcn_global_load_lds(
      (const __attribute__((address_space(1))) unsigned int*)g,
      (__attribute__((address_space(3))) unsigned int*)l, 16, 0, 0);
}

// ---------------------------------------------------------------------------
// k_prep (ATOMIC-FREE): per-block row-norm max + column-sum partials + bf16
// casts. Block b covers rows [b*64, b*64+64) of the concatenated [XB; Xbar].
// Outputs: blockmax[b], colpart[b][512]. Reduced by k_colred.
// (R4 profile: old atomic version ran 425us at VALUBusy 0.7% — 1.18M
//  atomicAdds over 1024 addresses + 2304 same-address atomicMax serialized.)
// ---------------------------------------------------------------------------
__global__ __launch_bounds__(256) void k_prep(
    const float* __restrict__ XB, const float* __restrict__ Xbar,
    unsigned short* __restrict__ XBb, unsigned short* __restrict__ Xbarb,
    float* __restrict__ blockmax, float* __restrict__ colpart, int N, int M) {
  const int wid = threadIdx.x >> 6, lane = threadIdx.x & 63;
  int rowBase = blockIdx.x * 64 + wid * 16;
  const float* src;
  unsigned short* dst;
  int r0;
  if (rowBase < N) { src = XB;   dst = XBb;   r0 = rowBase; }
  else             { src = Xbar; dst = Xbarb; r0 = rowBase - N; }
  float ca[8] = {0, 0, 0, 0, 0, 0, 0, 0};
  float rmax = 0.f;
  for (int i = 0; i < 16; ++i) {
    size_t base = (size_t)(r0 + i) * DD + lane * 8;
    float4 v0 = *(const float4*)&src[base];
    float4 v1 = *(const float4*)&src[base + 4];
    *(ushort4*)&dst[base]     = make_ushort4(f2bf(v0.x), f2bf(v0.y), f2bf(v0.z), f2bf(v0.w));
    *(ushort4*)&dst[base + 4] = make_ushort4(f2bf(v1.x), f2bf(v1.y), f2bf(v1.z), f2bf(v1.w));
    float ss = v0.x * v0.x + v0.y * v0.y + v0.z * v0.z + v0.w * v0.w +
               v1.x * v1.x + v1.y * v1.y + v1.z * v1.z + v1.w * v1.w;
    for (int k = 32; k; k >>= 1) ss += __shfl_xor(ss, k, 64);  // full-row sq-norm, wave-uniform
    rmax = fmaxf(rmax, ss);
    ca[0] += v0.x; ca[1] += v0.y; ca[2] += v0.z; ca[3] += v0.w;
    ca[4] += v1.x; ca[5] += v1.y; ca[6] += v1.z; ca[7] += v1.w;
  }
  __shared__ float scol[4][512];
  __shared__ float smax[4];
#pragma unroll
  for (int j = 0; j < 8; ++j) scol[wid][lane * 8 + j] = ca[j];
  if (lane == 0) smax[wid] = rmax;
  __syncthreads();
  const int t = threadIdx.x;
#pragma unroll
  for (int d = 0; d < 2; ++d) {
    int c = t + d * 256;
    colpart[(size_t)blockIdx.x * 512 + c] =
        scol[0][c] + scol[1][c] + scol[2][c] + scol[3][c];
  }
  if (t == 0)
    blockmax[blockIdx.x] = fmaxf(fmaxf(smax[0], smax[1]), fmaxf(smax[2], smax[3]));
}

// ---------------------------------------------------------------------------
// k_colred: <<<2, 512>>>. Block 0: sumXB[d] = sum colpart over XB blocks.
// Block 1: sumXbar[d] = sum over Xbar blocks; also cmax = max(blockmax).
// ---------------------------------------------------------------------------
__global__ __launch_bounds__(512) void k_colred(
    const float* __restrict__ colpart, const float* __restrict__ blockmax,
    float* __restrict__ sumXB, float* __restrict__ sumXbar,
    float* __restrict__ cmax, int nbXB, int nbTot) {
  const int d = threadIdx.x;
  if (blockIdx.x == 0) {
    float s = 0.f;
    for (int b = 0; b < nbXB; ++b) s += colpart[(size_t)b * 512 + d];
    sumXB[d] = s;
  } else {
    float s = 0.f;
    for (int b = nbXB; b < nbTot; ++b) s += colpart[(size_t)b * 512 + d];
    sumXbar[d] = s;
    float m = 0.f;
    for (int b = d; b < nbTot; b += 512) m = fmaxf(m, blockmax[b]);
    for (int k = 32; k; k >>= 1) m = fmaxf(m, __shfl_xor(m, k, 64));
    __shared__ float wmax[8];
    if ((d & 63) == 0) wmax[d >> 6] = m;
    __syncthreads();
    if (d == 0) {
      float mm = wmax[0];
#pragma unroll
      for (int w = 1; w < 8; ++w) mm = fmaxf(mm, wmax[w]);
      cmax[0] = mm;
    }
  }
}

// ---------------------------------------------------------------------------
// k_transpose: fp32 [R][C] -> bf16 transposed [C][R], 64x64 LDS tiles.
// ---------------------------------------------------------------------------
__global__ __launch_bounds__(256) void k_transpose(
    const float* __restrict__ in, unsigned short* __restrict__ out, int R, int C) {
  __shared__ float tile[64][65];
  const int r0 = blockIdx.y * 64, c0 = blockIdx.x * 64;
  const int t = threadIdx.x;
  {
    const int rl = t >> 4, c4 = (t & 15) * 4;
#pragma unroll
    for (int k = 0; k < 4; ++k) {
      float4 v = *(const float4*)&in[(size_t)(r0 + rl + 16 * k) * C + c0 + c4];
      tile[rl + 16 * k][c4 + 0] = v.x;
      tile[rl + 16 * k][c4 + 1] = v.y;
      tile[rl + 16 * k][c4 + 2] = v.z;
      tile[rl + 16 * k][c4 + 3] = v.w;
    }
  }
  __syncthreads();
  {
    const int cl = t >> 2, rs = (t & 3) * 16;
    short8 s0, s1;
#pragma unroll
    for (int i = 0; i < 8; ++i) s0[i] = (short)f2bf(tile[rs + i][cl]);
#pragma unroll
    for (int i = 0; i < 8; ++i) s1[i] = (short)f2bf(tile[rs + 8 + i][cl]);
    size_t ob = (size_t)(c0 + cl) * R + r0 + rs;
    *(short8*)&out[ob] = s0;
    *(short8*)&out[ob + 8] = s1;
  }
}

// ---------------------------------------------------------------------------
// Shared NT-GEMM core: 128x128 tile, BK=64, 256 thr (4 waves in 2x2),
// 16x16x32 bf16 MFMA, acc 4x4 frags/wave. Both operands row-major, k-contig.
// LDS staged via global_load_lds width=16 with XOR-16B-chunk swizzle applied
// on the GLOBAL source (LDS dest stays linear); ds_read applies same XOR.
// ---------------------------------------------------------------------------
__device__ __forceinline__ void gemm_core(
    const unsigned short* __restrict__ A, const unsigned short* __restrict__ B,
    int lda, int ldb, size_t arow0, size_t brow0, int kbase, int KT,
    unsigned short* sh, f32x4 acc[4][4]) {
  unsigned short* lA = sh;
  unsigned short* lB = sh + 8192;
  const int t = threadIdx.x, lane = t & 63, wid = t >> 6;
  const int frow = lane & 15, fgrp = lane >> 4;
  const int wr = (wid >> 1) * 64, wc = (wid & 1) * 64;
  for (int kt = 0; kt < KT; ++kt) {
    const int k0 = kbase + kt * 64;
    // stage A,B: 1024 16B-chunks each, 4 issues/thread/matrix
#pragma unroll
    for (int i = 0; i < 4; ++i) {
      int c4 = i * 256 + t;
      int r = c4 >> 3, c = c4 & 7;
      int cg = c ^ (r & 7);  // pre-swizzled global source; LDS linear
      gll16(&A[(arow0 + r) * (size_t)lda + k0 + cg * 8], &lA[(i * 256 + wid * 64) * 8]);
      gll16(&B[(brow0 + r) * (size_t)ldb + k0 + cg * 8], &lB[(i * 256 + wid * 64) * 8]);
    }
    __syncthreads();  // compiler drains vmcnt before barrier
#pragma unroll
    for (int kk = 0; kk < 2; ++kk) {
      short8 af[4], bf[4];
#pragma unroll
      for (int f = 0; f < 4; ++f) {
        int ra = wr + f * 16 + frow;
        int ca = (kk * 4 + fgrp) ^ (ra & 7);
        af[f] = *(const short8*)&lA[ra * 64 + ca * 8];
        int rb = wc + f * 16 + frow;
        int cb = (kk * 4 + fgrp) ^ (rb & 7);
        bf[f] = *(const short8*)&lB[rb * 64 + cb * 8];
      }
#pragma unroll
      for (int fr = 0; fr < 4; ++fr)
#pragma unroll
        for (int fc = 0; fc < 4; ++fc)
          acc[fr][fc] = __builtin_amdgcn_mfma_f32_16x16x32_bf16(af[fr], bf[fc], acc[fr][fc], 0, 0, 0);
    }
    __syncthreads();
  }
}

// ---------------------------------------------------------------------------
// k_scores (per m-chunk): E_q = expm1(scores/(sqrt(D)*cmax)) -> E_q[N][MQ]
// and ET_q[MQ][N] (bf16), plus rowsumE / colsumE atomic partials.
// ---------------------------------------------------------------------------
__global__ __launch_bounds__(256) void k_scores(
    const unsigned short* __restrict__ XBb, const unsigned short* __restrict__ Xbarb,
    unsigned short* __restrict__ E, unsigned short* __restrict__ ET,
    float* __restrict__ rowsumE, float* __restrict__ colsumE,
    const float* __restrict__ cmaxp, int N, int mq0, int MQ) {
  __shared__ __align__(16) unsigned short sh[17408];  // K-loop: 2x8192; epilogue: [128][136]
  f32x4 acc[4][4];
#pragma unroll
  for (int a = 0; a < 4; ++a)
#pragma unroll
    for (int b = 0; b < 4; ++b) acc[a][b] = (f32x4){0.f, 0.f, 0.f, 0.f};
  const size_t n0 = (size_t)blockIdx.y * 128;
  const int ml0 = blockIdx.x * 128;  // m-local within chunk
  gemm_core(XBb, Xbarb, DD, DD, n0, (size_t)(mq0 + ml0), 0, DD / 64, sh, acc);

  const float inv = 1.0f / (22.62741699796952f * cmaxp[0]);  // 1/(sqrt(512)*c_max)
  const int lane = threadIdx.x & 63, wid = threadIdx.x >> 6;
  const int frow = lane & 15, fgrp = lane >> 4;
  const int wr = (wid >> 1) * 64, wc = (wid & 1) * 64;
#pragma unroll
  for (int fr = 0; fr < 4; ++fr)
#pragma unroll
    for (int fc = 0; fc < 4; ++fc)
#pragma unroll
      for (int j = 0; j < 4; ++j) {
        int r = wr + fr * 16 + fgrp * 4 + j;   // C/D layout: row=(lane>>4)*4+j
        int c = wc + fc * 16 + frow;           //             col=lane&15
        sh[r * 136 + c] = f2bf(expm1f(acc[fr][fc][j] * inv));
      }
  __syncthreads();
  {  // E rows (half-row per thread) + rowsum
    const int r = threadIdx.x >> 1, h = threadIdx.x & 1;
    float rs = 0.f;
#pragma unroll
    for (int i = 0; i < 8; ++i) {
      short8 v = *(const short8*)&sh[r * 136 + h * 64 + i * 8];
#pragma unroll
      for (int j = 0; j < 8; ++j) rs += bf2f((unsigned short)v[j]);
      *(short8*)&E[(n0 + r) * (size_t)MQ + ml0 + h * 64 + i * 8] = v;
    }
    atomicAdd(&rowsumE[n0 + r], rs);
  }
  {  // ET columns (half-col per thread) + colsum
    const int c = threadIdx.x >> 1, v0 = (threadIdx.x & 1) * 64;
    float cs = 0.f;
#pragma unroll
    for (int i = 0; i < 8; ++i) {
      short8 s;
#pragma unroll
      for (int j = 0; j < 8; ++j) {
        unsigned short w = sh[(v0 + i * 8 + j) * 136 + c];
        cs += bf2f(w);
        s[j] = (short)w;
      }
      *(short8*)&ET[(size_t)(ml0 + c) * N + n0 + v0 + i * 8] = s;
    }
    atomicAdd(&colsumE[mq0 + ml0 + c], cs);
  }
}

// ---------------------------------------------------------------------------
// G3 per chunk: out1_raw[n][d] (store if accum==0, += otherwise).
// Division deferred to k_fin1.
// ---------------------------------------------------------------------------
__global__ __launch_bounds__(256) void k_gemm_acc(
    const unsigned short* __restrict__ A, const unsigned short* __restrict__ B,
    float* __restrict__ out, int lda, int ldb, int KT, int accum) {
  __shared__ __align__(16) unsigned short sh[16384];
  f32x4 acc[4][4];
#pragma unroll
  for (int a = 0; a < 4; ++a)
#pragma unroll
    for (int b = 0; b < 4; ++b) acc[a][b] = (f32x4){0.f, 0.f, 0.f, 0.f};
  const size_t a0 = (size_t)blockIdx.y * 128, b0 = (size_t)blockIdx.x * 128;
  gemm_core(A, B, lda, ldb, a0, b0, 0, KT, sh, acc);

  const int lane = threadIdx.x & 63, wid = threadIdx.x >> 6;
  const int frow = lane & 15, fgrp = lane >> 4;
  const int wr = (wid >> 1) * 64, wc = (wid & 1) * 64;
#pragma unroll
  for (int fr = 0; fr < 4; ++fr)
#pragma unroll
    for (int fc = 0; fc < 4; ++fc)
#pragma unroll
      for (int j = 0; j < 4; ++j) {
        size_t r = a0 + wr + fr * 16 + fgrp * 4 + j;
        size_t c = b0 + wc + fc * 16 + frow;
        size_t idx = r * DD + c;
        float v = acc[fr][fc][j];
        out[idx] = accum ? out[idx] + v : v;
      }
}

// ---------------------------------------------------------------------------
// G4 per chunk: partial[z][m_local][d] = (ET_q @ XBT)[m][d] over k-chunk z.
// Pure stores (no atomics).
// ---------------------------------------------------------------------------
__global__ __launch_bounds__(256) void k_gemm_part(
    const unsigned short* __restrict__ A, const unsigned short* __restrict__ B,
    float* __restrict__ part, int lda, int KT, int kchunk, int MQ) {
  __shared__ __align__(16) unsigned short sh[16384];
  f32x4 acc[4][4];
#pragma unroll
  for (int a = 0; a < 4; ++a)
#pragma unroll
    for (int b = 0; b < 4; ++b) acc[a][b] = (f32x4){0.f, 0.f, 0.f, 0.f};
  const size_t a0 = (size_t)blockIdx.y * 128, b0 = (size_t)blockIdx.x * 128;
  gemm_core(A, B, lda, lda, a0, b0, blockIdx.z * kchunk, KT, sh, acc);

  float* pz = part + (size_t)blockIdx.z * MQ * DD;
  const int lane = threadIdx.x & 63, wid = threadIdx.x >> 6;
  const int frow = lane & 15, fgrp = lane >> 4;
  const int wr = (wid >> 1) * 64, wc = (wid & 1) * 64;
#pragma unroll
  for (int fr = 0; fr < 4; ++fr)
#pragma unroll
    for (int fc = 0; fc < 4; ++fc)
#pragma unroll
      for (int j = 0; j < 4; ++j) {
        size_t r = a0 + wr + fr * 16 + fgrp * 4 + j;
        size_t c = b0 + wc + fc * 16 + frow;
        pz[r * DD + c] = acc[fr][fc][j];
      }
}

// out2 chunk: out2[m][d] = (sumXB[d] + sum_z partial[z][m][d]) / (Nf + colsumE[m])
__global__ void k_reduce2(const float* __restrict__ part, float* __restrict__ out2,
                          const float* __restrict__ sumXB, const float* __restrict__ colsumE,
                          int MQ, int Z, float Nf) {
  size_t idx4 = ((size_t)blockIdx.x * 256 + threadIdx.x) * 4;
  int ml = (int)(idx4 >> 9), d = (int)(idx4 & (DD - 1));
  float4 s = make_float4(0.f, 0.f, 0.f, 0.f);
  for (int z = 0; z < Z; ++z) {
    float4 p = *(const float4*)&part[(size_t)z * MQ * DD + idx4];
    s.x += p.x; s.y += p.y; s.z += p.z; s.w += p.w;
  }
  float4 sx = *(const float4*)&sumXB[d];
  float den = 1.0f / (Nf + colsumE[ml]);
  float4 o = make_float4((sx.x + s.x) * den, (sx.y + s.y) * den,
                         (sx.z + s.z) * den, (sx.w + s.w) * den);
  *(float4*)&out2[idx4] = o;
}

// out1 final: out1[n][d] = (sumXbar[d] + raw) / (Mf + rowsumE[n])
__global__ void k_fin1(float* __restrict__ o, const float* __restrict__ sumXbar,
                       const float* __restrict__ rowsumE, float Mf) {
  size_t idx4 = ((size_t)blockIdx.x * 256 + threadIdx.x) * 4;
  int n = (int)(idx4 >> 9), d = (int)(idx4 & (DD - 1));
  float4 raw = *(const float4*)&o[idx4];
  float4 sx = *(const float4*)&sumXbar[d];
  float den = 1.0f / (Mf + rowsumE[n]);
  float4 r = make_float4((sx.x + raw.x) * den, (sx.y + raw.y) * den,
                         (sx.z + raw.z) * den, (sx.w + raw.w) * den);
  *(float4*)&o[idx4] = r;
}

__global__ void k_wsmark(float* o, float a) { o[0] = a; }

// ---------------------------------------------------------------------------
extern "C" void kernel_launch(void* const* d_in, const int* in_sizes, int n_in,
                              void* d_out, int out_size, void* d_ws, size_t ws_size,
                              hipStream_t stream) {
  const float* XB = (const float*)d_in[0];
  const float* Xbar = (const float*)d_in[1];
  const int N = in_sizes[0] / DD;  // 32768
  const int M = in_sizes[1] / DD;  // 4096
  float* out = (float*)d_out;
  const int Z = 16, kchunk = N / Z, KT4 = kchunk / 64;
  const int nb = (N + M) / 64;  // prep blocks

  // Pick largest m-chunk that fits the workspace.
  int MQ = 1024;
  size_t off = 0;
  char* ws = (char*)d_ws;
  auto plan = [&](int mq) {
    size_t o = 0;
    auto tk = [&](size_t b) { o = (o + b + 255) & ~(size_t)255; };
    tk(4); tk((size_t)N * 4); tk((size_t)M * 4); tk(DD * 4); tk(DD * 4);   // head
    tk((size_t)nb * 4); tk((size_t)nb * 512 * 4);                          // blockmax, colpart
    tk((size_t)N * DD * 2); tk((size_t)M * DD * 2);                        // XBb, Xbarb
    tk((size_t)N * DD * 2); tk((size_t)M * DD * 2);                        // XBT, XbarT
    tk((size_t)N * mq * 2); tk((size_t)mq * N * 2);                        // E_q, ET_q
    tk((size_t)Z * mq * DD * 4);                                           // partials
    return o;
  };
  while (MQ > 128 && plan(MQ) > ws_size) MQ >>= 1;
  if (plan(MQ) > ws_size) {
    hipMemsetAsync(d_out, 0, (size_t)out_size * 4, stream);
    k_wsmark<<<1, 1, 0, stream>>>(out, (float)ws_size);
    return;
  }

  auto take = [&](size_t bytes) {
    char* p = ws + off;
    off = (off + bytes + 255) & ~(size_t)255;
    return p;
  };
  float* cmax = (float*)take(4);
  float* rowsumE = (float*)take((size_t)N * 4);
  float* colsumE = (float*)take((size_t)M * 4);
  float* sumXB = (float*)take(DD * 4);
  float* sumXbar = (float*)take(DD * 4);
  size_t headBytes = off;  // rowsumE/colsumE need zero-init (atomic accumulators)
  float* blockmax = (float*)take((size_t)nb * 4);
  float* colpart = (float*)take((size_t)nb * 512 * 4);
  unsigned short* XBb = (unsigned short*)take((size_t)N * DD * 2);
  unsigned short* Xbarb = (unsigned short*)take((size_t)M * DD * 2);
  unsigned short* XBT = (unsigned short*)take((size_t)N * DD * 2);
  unsigned short* XbarT = (unsigned short*)take((size_t)M * DD * 2);
  unsigned short* E = (unsigned short*)take((size_t)N * MQ * 2);
  unsigned short* ET = (unsigned short*)take((size_t)MQ * N * 2);
  float* part = (float*)take((size_t)Z * MQ * DD * 4);

  hipMemsetAsync(ws, 0, headBytes, stream);  // zero rowsumE/colsumE (+cmax, harmless)

  k_prep<<<nb, 256, 0, stream>>>(XB, Xbar, XBb, Xbarb, blockmax, colpart, N, M);
  k_colred<<<2, 512, 0, stream>>>(colpart, blockmax, sumXB, sumXbar, cmax, N / 64, nb);
  k_transpose<<<dim3(DD / 64, N / 64), 256, 0, stream>>>(XB, XBT, N, DD);
  k_transpose<<<dim3(DD / 64, M / 64), 256, 0, stream>>>(Xbar, XbarT, M, DD);

  for (int mq0 = 0; mq0 < M; mq0 += MQ) {
    k_scores<<<dim3(MQ / 128, N / 128), 256, 0, stream>>>(
        XBb, Xbarb, E, ET, rowsumE, colsumE, cmax, N, mq0, MQ);
    k_gemm_acc<<<dim3(DD / 128, N / 128), 256, 0, stream>>>(
        E, XbarT + mq0, out, MQ, M, MQ / 64, mq0 > 0 ? 1 : 0);
    k_gemm_part<<<dim3(DD / 128, MQ / 128, Z), 256, 0, stream>>>(
        ET, XBT, part, N, KT4, kchunk, MQ);
    k_reduce2<<<(MQ * DD) / 1024, 256, 0, stream>>>(
        part, out + (size_t)N * DD + (size_t)mq0 * DD, sumXB, colsumE + mq0, MQ, Z, (float)N);
  }
  k_fin1<<<((size_t)N * DD) / 1024, 256, 0, stream>>>(out, sumXbar, rowsumE, (float)M);
}

// Round 8
// 1517.352 us; speedup vs baseline: 1.2051x; 1.0196x over previous
//
#include <hip/hip_runtime.h>
#include <math.h>

#define DD 512

typedef __attribute__((ext_vector_type(8))) short short8;
typedef __attribute__((ext_vector_type(4))) float f32x4;

__device__ __forceinline__ unsigned short f2bf(float x) {
  unsigned u = __float_as_uint(x);
  u = (u + 0x7FFFu + ((u >> 16) & 1u)) >> 16;  // RNE; no NaN expected
  return (unsigned short)u;
}
__device__ __forceinline__ float bf2f(unsigned short b) {
  return __uint_as_float(((unsigned)b) << 16);
}

__device__ __forceinline__ void gll16(const void* g, void* l) {
  __builtin_amdgcn_global_load_lds(
      (const __attribute__((address_space(1))) unsigned int*)g,
      (__attribute__((address_space(3))) unsigned int*)l, 16, 0, 0);
}

// XCD-aware bijective block swizzle (T1): consecutive-XCD round-robin ->
// contiguous per-XCD chunks so panel-sharing neighbor blocks hit the same L2.
// Requires total block count % 8 == 0 (all call sites satisfy this at every
// MQ fallback: 2048/1024/512/256/128/64 blocks).
__device__ __forceinline__ void swz_bid(int& bx, int& by, int& bz) {
  unsigned gx = gridDim.x, gy = gridDim.y, gz = gridDim.z;
  unsigned n = gx * gy * gz;
  unsigned id = blockIdx.x + gx * (blockIdx.y + gy * blockIdx.z);
  unsigned q = n >> 3;
  unsigned s = (id & 7u) * q + (id >> 3);
  bx = s % gx;
  unsigned t = s / gx;
  by = t % gy;
  bz = t / gy;
}

// ---------------------------------------------------------------------------
// k_prep (ATOMIC-FREE): per-block row-norm max + column-sum partials + bf16
// casts. Block b covers rows [b*64, b*64+64) of the concatenated [XB; Xbar].
// ---------------------------------------------------------------------------
__global__ __launch_bounds__(256) void k_prep(
    const float* __restrict__ XB, const float* __restrict__ Xbar,
    unsigned short* __restrict__ XBb, unsigned short* __restrict__ Xbarb,
    float* __restrict__ blockmax, float* __restrict__ colpart, int N, int M) {
  const int wid = threadIdx.x >> 6, lane = threadIdx.x & 63;
  int rowBase = blockIdx.x * 64 + wid * 16;
  const float* src;
  unsigned short* dst;
  int r0;
  if (rowBase < N) { src = XB;   dst = XBb;   r0 = rowBase; }
  else             { src = Xbar; dst = Xbarb; r0 = rowBase - N; }
  float ca[8] = {0, 0, 0, 0, 0, 0, 0, 0};
  float rmax = 0.f;
  for (int i = 0; i < 16; ++i) {
    size_t base = (size_t)(r0 + i) * DD + lane * 8;
    float4 v0 = *(const float4*)&src[base];
    float4 v1 = *(const float4*)&src[base + 4];
    *(ushort4*)&dst[base]     = make_ushort4(f2bf(v0.x), f2bf(v0.y), f2bf(v0.z), f2bf(v0.w));
    *(ushort4*)&dst[base + 4] = make_ushort4(f2bf(v1.x), f2bf(v1.y), f2bf(v1.z), f2bf(v1.w));
    float ss = v0.x * v0.x + v0.y * v0.y + v0.z * v0.z + v0.w * v0.w +
               v1.x * v1.x + v1.y * v1.y + v1.z * v1.z + v1.w * v1.w;
    for (int k = 32; k; k >>= 1) ss += __shfl_xor(ss, k, 64);  // full-row sq-norm
    rmax = fmaxf(rmax, ss);
    ca[0] += v0.x; ca[1] += v0.y; ca[2] += v0.z; ca[3] += v0.w;
    ca[4] += v1.x; ca[5] += v1.y; ca[6] += v1.z; ca[7] += v1.w;
  }
  __shared__ float scol[4][512];
  __shared__ float smax[4];
#pragma unroll
  for (int j = 0; j < 8; ++j) scol[wid][lane * 8 + j] = ca[j];
  if (lane == 0) smax[wid] = rmax;
  __syncthreads();
  const int t = threadIdx.x;
#pragma unroll
  for (int d = 0; d < 2; ++d) {
    int c = t + d * 256;
    colpart[(size_t)blockIdx.x * 512 + c] =
        scol[0][c] + scol[1][c] + scol[2][c] + scol[3][c];
  }
  if (t == 0)
    blockmax[blockIdx.x] = fmaxf(fmaxf(smax[0], smax[1]), fmaxf(smax[2], smax[3]));
}

// ---------------------------------------------------------------------------
// k_colred: <<<2, 512>>>. Block 0: sumXB; block 1: sumXbar + cmax.
// ---------------------------------------------------------------------------
__global__ __launch_bounds__(512) void k_colred(
    const float* __restrict__ colpart, const float* __restrict__ blockmax,
    float* __restrict__ sumXB, float* __restrict__ sumXbar,
    float* __restrict__ cmax, int nbXB, int nbTot) {
  const int d = threadIdx.x;
  if (blockIdx.x == 0) {
    float s = 0.f;
    for (int b = 0; b < nbXB; ++b) s += colpart[(size_t)b * 512 + d];
    sumXB[d] = s;
  } else {
    float s = 0.f;
    for (int b = nbXB; b < nbTot; ++b) s += colpart[(size_t)b * 512 + d];
    sumXbar[d] = s;
    float m = 0.f;
    for (int b = d; b < nbTot; b += 512) m = fmaxf(m, blockmax[b]);
    for (int k = 32; k; k >>= 1) m = fmaxf(m, __shfl_xor(m, k, 64));
    __shared__ float wmax[8];
    if ((d & 63) == 0) wmax[d >> 6] = m;
    __syncthreads();
    if (d == 0) {
      float mm = wmax[0];
#pragma unroll
      for (int w = 1; w < 8; ++w) mm = fmaxf(mm, wmax[w]);
      cmax[0] = mm;
    }
  }
}

// ---------------------------------------------------------------------------
// k_transpose: fp32 [R][C] -> bf16 transposed [C][R], 64x64 LDS tiles.
// ---------------------------------------------------------------------------
__global__ __launch_bounds__(256) void k_transpose(
    const float* __restrict__ in, unsigned short* __restrict__ out, int R, int C) {
  __shared__ float tile[64][65];
  const int r0 = blockIdx.y * 64, c0 = blockIdx.x * 64;
  const int t = threadIdx.x;
  {
    const int rl = t >> 4, c4 = (t & 15) * 4;
#pragma unroll
    for (int k = 0; k < 4; ++k) {
      float4 v = *(const float4*)&in[(size_t)(r0 + rl + 16 * k) * C + c0 + c4];
      tile[rl + 16 * k][c4 + 0] = v.x;
      tile[rl + 16 * k][c4 + 1] = v.y;
      tile[rl + 16 * k][c4 + 2] = v.z;
      tile[rl + 16 * k][c4 + 3] = v.w;
    }
  }
  __syncthreads();
  {
    const int cl = t >> 2, rs = (t & 3) * 16;
    short8 s0, s1;
#pragma unroll
    for (int i = 0; i < 8; ++i) s0[i] = (short)f2bf(tile[rs + i][cl]);
#pragma unroll
    for (int i = 0; i < 8; ++i) s1[i] = (short)f2bf(tile[rs + 8 + i][cl]);
    size_t ob = (size_t)(c0 + cl) * R + r0 + rs;
    *(short8*)&out[ob] = s0;
    *(short8*)&out[ob + 8] = s1;
  }
}

// ---------------------------------------------------------------------------
// Shared NT-GEMM core: 128x128 tile, BK=64, 256 thr (4 waves in 2x2),
// 16x16x32 bf16 MFMA, acc 4x4 frags/wave. Both operands row-major, k-contig.
// ---------------------------------------------------------------------------
__device__ __forceinline__ void gemm_core(
    const unsigned short* __restrict__ A, const unsigned short* __restrict__ B,
    int lda, int ldb, size_t arow0, size_t brow0, int kbase, int KT,
    unsigned short* sh, f32x4 acc[4][4]) {
  unsigned short* lA = sh;
  unsigned short* lB = sh + 8192;
  const int t = threadIdx.x, lane = t & 63, wid = t >> 6;
  const int frow = lane & 15, fgrp = lane >> 4;
  const int wr = (wid >> 1) * 64, wc = (wid & 1) * 64;
  for (int kt = 0; kt < KT; ++kt) {
    const int k0 = kbase + kt * 64;
#pragma unroll
    for (int i = 0; i < 4; ++i) {
      int c4 = i * 256 + t;
      int r = c4 >> 3, c = c4 & 7;
      int cg = c ^ (r & 7);  // pre-swizzled global source; LDS linear
      gll16(&A[(arow0 + r) * (size_t)lda + k0 + cg * 8], &lA[(i * 256 + wid * 64) * 8]);
      gll16(&B[(brow0 + r) * (size_t)ldb + k0 + cg * 8], &lB[(i * 256 + wid * 64) * 8]);
    }
    __syncthreads();  // compiler drains vmcnt before barrier
#pragma unroll
    for (int kk = 0; kk < 2; ++kk) {
      short8 af[4], bf[4];
#pragma unroll
      for (int f = 0; f < 4; ++f) {
        int ra = wr + f * 16 + frow;
        int ca = (kk * 4 + fgrp) ^ (ra & 7);
        af[f] = *(const short8*)&lA[ra * 64 + ca * 8];
        int rb = wc + f * 16 + frow;
        int cb = (kk * 4 + fgrp) ^ (rb & 7);
        bf[f] = *(const short8*)&lB[rb * 64 + cb * 8];
      }
#pragma unroll
      for (int fr = 0; fr < 4; ++fr)
#pragma unroll
        for (int fc = 0; fc < 4; ++fc)
          acc[fr][fc] = __builtin_amdgcn_mfma_f32_16x16x32_bf16(af[fr], bf[fc], acc[fr][fc], 0, 0, 0);
    }
    __syncthreads();
  }
}

// ---------------------------------------------------------------------------
// k_scores (per m-chunk): E_q = expm1(scores/(sqrt(D)*cmax)) -> E_q[N][MQ]
// and ET_q[MQ][N] (bf16), plus rowsumE / colsumE atomic partials.
// R5 profile: 160us/dispatch, MfmaUtil 8%, epilogue-dominated; libm expm1f
// (~25 inst + TRANS pipe, x64/thread) was ~70% of epilogue work. |x| <=
// 1/sqrt(512)=0.0442 (Cauchy-Schwarz), so 4-term Taylor err ~x^5/120 = 1.4e-9.
// ---------------------------------------------------------------------------
__global__ __launch_bounds__(256) void k_scores(
    const unsigned short* __restrict__ XBb, const unsigned short* __restrict__ Xbarb,
    unsigned short* __restrict__ E, unsigned short* __restrict__ ET,
    float* __restrict__ rowsumE, float* __restrict__ colsumE,
    const float* __restrict__ cmaxp, int N, int mq0, int MQ) {
  __shared__ __align__(16) unsigned short sh[17408];  // K-loop: 2x8192; epilogue: [128][136]
  f32x4 acc[4][4];
#pragma unroll
  for (int a = 0; a < 4; ++a)
#pragma unroll
    for (int b = 0; b < 4; ++b) acc[a][b] = (f32x4){0.f, 0.f, 0.f, 0.f};
  int bx, by, bz;
  swz_bid(bx, by, bz);
  const size_t n0 = (size_t)by * 128;
  const int ml0 = bx * 128;  // m-local within chunk
  gemm_core(XBb, Xbarb, DD, DD, n0, (size_t)(mq0 + ml0), 0, DD / 64, sh, acc);

  const float inv = 1.0f / (22.62741699796952f * cmaxp[0]);  // 1/(sqrt(512)*c_max)
  const int lane = threadIdx.x & 63, wid = threadIdx.x >> 6;
  const int frow = lane & 15, fgrp = lane >> 4;
  const int wr = (wid >> 1) * 64, wc = (wid & 1) * 64;
#pragma unroll
  for (int fr = 0; fr < 4; ++fr)
#pragma unroll
    for (int fc = 0; fc < 4; ++fc)
#pragma unroll
      for (int j = 0; j < 4; ++j) {
        int r = wr + fr * 16 + fgrp * 4 + j;   // C/D layout: row=(lane>>4)*4+j
        int c = wc + fc * 16 + frow;           //             col=lane&15
        float x = acc[fr][fc][j] * inv;
        float e = x * (1.f + x * (0.5f + x * (0.16666667f + x * 0.041666668f)));
        sh[r * 136 + c] = f2bf(e);
      }
  __syncthreads();
  {  // E rows (half-row per thread) + rowsum
    const int r = threadIdx.x >> 1, h = threadIdx.x & 1;
    float rs = 0.f;
#pragma unroll
    for (int i = 0; i < 8; ++i) {
      short8 v = *(const short8*)&sh[r * 136 + h * 64 + i * 8];
#pragma unroll
      for (int j = 0; j < 8; ++j) rs += bf2f((unsigned short)v[j]);
      *(short8*)&E[(n0 + r) * (size_t)MQ + ml0 + h * 64 + i * 8] = v;
    }
    atomicAdd(&rowsumE[n0 + r], rs);
  }
  {  // ET columns (half-col per thread) + colsum
    const int c = threadIdx.x >> 1, v0 = (threadIdx.x & 1) * 64;
    float cs = 0.f;
#pragma unroll
    for (int i = 0; i < 8; ++i) {
      short8 s;
#pragma unroll
      for (int j = 0; j < 8; ++j) {
        unsigned short w = sh[(v0 + i * 8 + j) * 136 + c];
        cs += bf2f(w);
        s[j] = (short)w;
      }
      *(short8*)&ET[(size_t)(ml0 + c) * N + n0 + v0 + i * 8] = s;
    }
    atomicAdd(&colsumE[mq0 + ml0 + c], cs);
  }
}

// ---------------------------------------------------------------------------
// G3 per chunk: out1_raw[n][d] (store if accum==0, += otherwise).
// ---------------------------------------------------------------------------
__global__ __launch_bounds__(256) void k_gemm_acc(
    const unsigned short* __restrict__ A, const unsigned short* __restrict__ B,
    float* __restrict__ out, int lda, int ldb, int KT, int accum) {
  __shared__ __align__(16) unsigned short sh[16384];
  f32x4 acc[4][4];
#pragma unroll
  for (int a = 0; a < 4; ++a)
#pragma unroll
    for (int b = 0; b < 4; ++b) acc[a][b] = (f32x4){0.f, 0.f, 0.f, 0.f};
  int bx, by, bz;
  swz_bid(bx, by, bz);
  const size_t a0 = (size_t)by * 128, b0 = (size_t)bx * 128;
  gemm_core(A, B, lda, ldb, a0, b0, 0, KT, sh, acc);

  const int lane = threadIdx.x & 63, wid = threadIdx.x >> 6;
  const int frow = lane & 15, fgrp = lane >> 4;
  const int wr = (wid >> 1) * 64, wc = (wid & 1) * 64;
#pragma unroll
  for (int fr = 0; fr < 4; ++fr)
#pragma unroll
    for (int fc = 0; fc < 4; ++fc)
#pragma unroll
      for (int j = 0; j < 4; ++j) {
        size_t r = a0 + wr + fr * 16 + fgrp * 4 + j;
        size_t c = b0 + wc + fc * 16 + frow;
        size_t idx = r * DD + c;
        float v = acc[fr][fc][j];
        out[idx] = accum ? out[idx] + v : v;
      }
}

// ---------------------------------------------------------------------------
// G4 per chunk: partial[z][m_local][d] = (ET_q @ XBT)[m][d] over k-chunk z.
// ---------------------------------------------------------------------------
__global__ __launch_bounds__(256) void k_gemm_part(
    const unsigned short* __restrict__ A, const unsigned short* __restrict__ B,
    float* __restrict__ part, int lda, int KT, int kchunk, int MQ) {
  __shared__ __align__(16) unsigned short sh[16384];
  f32x4 acc[4][4];
#pragma unroll
  for (int a = 0; a < 4; ++a)
#pragma unroll
    for (int b = 0; b < 4; ++b) acc[a][b] = (f32x4){0.f, 0.f, 0.f, 0.f};
  int bx, by, bz;
  swz_bid(bx, by, bz);
  const size_t a0 = (size_t)by * 128, b0 = (size_t)bx * 128;
  gemm_core(A, B, lda, lda, a0, b0, bz * kchunk, KT, sh, acc);

  float* pz = part + (size_t)bz * MQ * DD;
  const int lane = threadIdx.x & 63, wid = threadIdx.x >> 6;
  const int frow = lane & 15, fgrp = lane >> 4;
  const int wr = (wid >> 1) * 64, wc = (wid & 1) * 64;
#pragma unroll
  for (int fr = 0; fr < 4; ++fr)
#pragma unroll
    for (int fc = 0; fc < 4; ++fc)
#pragma unroll
      for (int j = 0; j < 4; ++j) {
        size_t r = a0 + wr + fr * 16 + fgrp * 4 + j;
        size_t c = b0 + wc + fc * 16 + frow;
        pz[r * DD + c] = acc[fr][fc][j];
      }
}

// out2 chunk: out2[m][d] = (sumXB[d] + sum_z partial[z][m][d]) / (Nf + colsumE[m])
__global__ void k_reduce2(const float* __restrict__ part, float* __restrict__ out2,
                          const float* __restrict__ sumXB, const float* __restrict__ colsumE,
                          int MQ, int Z, float Nf) {
  size_t idx4 = ((size_t)blockIdx.x * 256 + threadIdx.x) * 4;
  int ml = (int)(idx4 >> 9), d = (int)(idx4 & (DD - 1));
  float4 s = make_float4(0.f, 0.f, 0.f, 0.f);
  for (int z = 0; z < Z; ++z) {
    float4 p = *(const float4*)&part[(size_t)z * MQ * DD + idx4];
    s.x += p.x; s.y += p.y; s.z += p.z; s.w += p.w;
  }
  float4 sx = *(const float4*)&sumXB[d];
  float den = 1.0f / (Nf + colsumE[ml]);
  float4 o = make_float4((sx.x + s.x) * den, (sx.y + s.y) * den,
                         (sx.z + s.z) * den, (sx.w + s.w) * den);
  *(float4*)&out2[idx4] = o;
}

// out1 final: out1[n][d] = (sumXbar[d] + raw) / (Mf + rowsumE[n])
__global__ void k_fin1(float* __restrict__ o, const float* __restrict__ sumXbar,
                       const float* __restrict__ rowsumE, float Mf) {
  size_t idx4 = ((size_t)blockIdx.x * 256 + threadIdx.x) * 4;
  int n = (int)(idx4 >> 9), d = (int)(idx4 & (DD - 1));
  float4 raw = *(const float4*)&o[idx4];
  float4 sx = *(const float4*)&sumXbar[d];
  float den = 1.0f / (Mf + rowsumE[n]);
  float4 r = make_float4((sx.x + raw.x) * den, (sx.y + raw.y) * den,
                         (sx.z + raw.z) * den, (sx.w + raw.w) * den);
  *(float4*)&o[idx4] = r;
}

__global__ void k_wsmark(float* o, float a) { o[0] = a; }

// ---------------------------------------------------------------------------
extern "C" void kernel_launch(void* const* d_in, const int* in_sizes, int n_in,
                              void* d_out, int out_size, void* d_ws, size_t ws_size,
                              hipStream_t stream) {
  const float* XB = (const float*)d_in[0];
  const float* Xbar = (const float*)d_in[1];
  const int N = in_sizes[0] / DD;  // 32768
  const int M = in_sizes[1] / DD;  // 4096
  float* out = (float*)d_out;
  const int Z = 16, kchunk = N / Z, KT4 = kchunk / 64;
  const int nb = (N + M) / 64;  // prep blocks

  // Pick largest m-chunk that fits the workspace.
  int MQ = 1024;
  size_t off = 0;
  char* ws = (char*)d_ws;
  auto plan = [&](int mq) {
    size_t o = 0;
    auto tk = [&](size_t b) { o = (o + b + 255) & ~(size_t)255; };
    tk(4); tk((size_t)N * 4); tk((size_t)M * 4); tk(DD * 4); tk(DD * 4);   // head
    tk((size_t)nb * 4); tk((size_t)nb * 512 * 4);                          // blockmax, colpart
    tk((size_t)N * DD * 2); tk((size_t)M * DD * 2);                        // XBb, Xbarb
    tk((size_t)N * DD * 2); tk((size_t)M * DD * 2);                        // XBT, XbarT
    tk((size_t)N * mq * 2); tk((size_t)mq * N * 2);                        // E_q, ET_q
    tk((size_t)Z * mq * DD * 4);                                           // partials
    return o;
  };
  while (MQ > 128 && plan(MQ) > ws_size) MQ >>= 1;
  if (plan(MQ) > ws_size) {
    hipMemsetAsync(d_out, 0, (size_t)out_size * 4, stream);
    k_wsmark<<<1, 1, 0, stream>>>(out, (float)ws_size);
    return;
  }

  auto take = [&](size_t bytes) {
    char* p = ws + off;
    off = (off + bytes + 255) & ~(size_t)255;
    return p;
  };
  float* cmax = (float*)take(4);
  float* rowsumE = (float*)take((size_t)N * 4);
  float* colsumE = (float*)take((size_t)M * 4);
  float* sumXB = (float*)take(DD * 4);
  float* sumXbar = (float*)take(DD * 4);
  size_t headBytes = off;  // rowsumE/colsumE need zero-init (atomic accumulators)
  float* blockmax = (float*)take((size_t)nb * 4);
  float* colpart = (float*)take((size_t)nb * 512 * 4);
  unsigned short* XBb = (unsigned short*)take((size_t)N * DD * 2);
  unsigned short* Xbarb = (unsigned short*)take((size_t)M * DD * 2);
  unsigned short* XBT = (unsigned short*)take((size_t)N * DD * 2);
  unsigned short* XbarT = (unsigned short*)take((size_t)M * DD * 2);
  unsigned short* E = (unsigned short*)take((size_t)N * MQ * 2);
  unsigned short* ET = (unsigned short*)take((size_t)MQ * N * 2);
  float* part = (float*)take((size_t)Z * MQ * DD * 4);

  hipMemsetAsync(ws, 0, headBytes, stream);  // zero rowsumE/colsumE (+cmax, harmless)

  k_prep<<<nb, 256, 0, stream>>>(XB, Xbar, XBb, Xbarb, blockmax, colpart, N, M);
  k_colred<<<2, 512, 0, stream>>>(colpart, blockmax, sumXB, sumXbar, cmax, N / 64, nb);
  k_transpose<<<dim3(DD / 64, N / 64), 256, 0, stream>>>(XB, XBT, N, DD);
  k_transpose<<<dim3(DD / 64, M / 64), 256, 0, stream>>>(Xbar, XbarT, M, DD);

  for (int mq0 = 0; mq0 < M; mq0 += MQ) {
    k_scores<<<dim3(MQ / 128, N / 128), 256, 0, stream>>>(
        XBb, Xbarb, E, ET, rowsumE, colsumE, cmax, N, mq0, MQ);
    k_gemm_acc<<<dim3(DD / 128, N / 128), 256, 0, stream>>>(
        E, XbarT + mq0, out, MQ, M, MQ / 64, mq0 > 0 ? 1 : 0);
    k_gemm_part<<<dim3(DD / 128, MQ / 128, Z), 256, 0, stream>>>(
        ET, XBT, part, N, KT4, kchunk, MQ);
    k_reduce2<<<(MQ * DD) / 1024, 256, 0, stream>>>(
        part, out + (size_t)N * DD + (size_t)mq0 * DD, sumXB, colsumE + mq0, MQ, Z, (float)N);
  }
  k_fin1<<<((size_t)N * DD) / 1024, 256, 0, stream>>>(out, sumXbar, rowsumE, (float)M);
}